// Round 17
// baseline (1313.321 us; speedup 1.0000x reference)
//
#include <hip/hip_runtime.h>
#include <hip/hip_bf16.h>
#include <hip/hip_fp16.h>

// Tight stage-1 activations. Per-sample slot = region A + region B (halves).
// A: conv5 out [8cg][70][16][8]=71680. B: conv4-pool out [4cg][72][16][8]=36864.
// conv1/conv2/conv3 outs live in LDS only (fused band kernel).
#define TA 71680
#define SLOT 108544
// conv6 output halves per sample: [8 cg][34 rows][11 cols][8 ci], row stride 11
#define C6N 23936

typedef _Float16 v8h __attribute__((ext_vector_type(8)));
typedef float v4f __attribute__((ext_vector_type(4)));
typedef unsigned short u16x8 __attribute__((ext_vector_type(8)));

__device__ inline float h2f(unsigned short u) {
    union { unsigned short s; _Float16 h; } v; v.s = u; return (float)v.h;
}
__device__ inline unsigned short f2h(float f) {
    union { unsigned short s; _Float16 h; } v; v.h = (_Float16)f; return v.s;
}

// ---------------------------------------------------------------------------
// conv1 weight repack (fp32): [co][1][kh][kw] -> [k][co], BN folded; emits t.
// ---------------------------------------------------------------------------
__global__ void repack_k(const float* __restrict__ W, const float* __restrict__ bb,
                         const float* __restrict__ gg, const float* __restrict__ be,
                         const float* __restrict__ mm, const float* __restrict__ vv,
                         float* __restrict__ wOut, float* __restrict__ tOut,
                         int CIN, int KHW, int COUT)
{
    int gid = blockIdx.x * 256 + threadIdx.x;
    if (gid < COUT) {
        float s = gg[gid] * rsqrtf(vv[gid] + 1e-5f);
        tOut[gid] = (bb[gid] - mm[gid]) * s + be[gid];
    }
    int tot = CIN * KHW * COUT;
    if (gid >= tot) return;
    int co = gid % COUT;
    int rest = gid / COUT;
    int k = rest % KHW;
    int ci = rest / KHW;
    float s = gg[co] * rsqrtf(vv[co] + 1e-5f);
    wOut[gid] = W[(co * CIN + ci) * KHW + k] * s;
}

// ---------------------------------------------------------------------------
// MFMA B-fragment repack for 3x3 layers (conv2..conv6), fp16.
// ---------------------------------------------------------------------------
__global__ void repack_mfma_k(const float* __restrict__ W, const float* __restrict__ bb,
                              const float* __restrict__ gg, const float* __restrict__ be,
                              const float* __restrict__ mm, const float* __restrict__ vv,
                              unsigned short* __restrict__ frag, float* __restrict__ tOut,
                              int CIN, int NT, int HALVES)
{
    int gid = blockIdx.x * 256 + threadIdx.x;
    int COUT = NT * 16;
    if (gid < COUT) {
        float s = gg[gid] * rsqrtf(vv[gid] + 1e-5f);
        tOut[gid] = (bb[gid] - mm[gid]) * s + be[gid];
    }
    int tot = 9 * HALVES * NT * 512;
    if (gid >= tot) return;
    int j    = gid & 7;
    int lane = (gid >> 3) & 63;
    int nt   = (gid >> 9) % NT;
    int rest = (gid >> 9) / NT;
    int half = rest % HALVES;
    int khw  = rest / HALVES;
    int ci   = half * 32 + (lane >> 4) * 8 + j;
    int co   = nt * 16 + (lane & 15);
    int kh   = khw / 3, kw = khw % 3;
    float s = gg[co] * rsqrtf(vv[co] + 1e-5f);
    frag[gid] = f2h(W[((co * CIN + ci) * 3 + kh) * 3 + kw] * s);
}

// ---------------------------------------------------------------------------
// Conv7 weight repack into MFMA B-fragment order (12x9 kernel), fp16.
// ---------------------------------------------------------------------------
__global__ void repack7_k(const float* __restrict__ W, const float* __restrict__ bb,
                          const float* __restrict__ gg, const float* __restrict__ be,
                          const float* __restrict__ mm, const float* __restrict__ vv,
                          unsigned short* __restrict__ frag, float* __restrict__ tOut)
{
    int gid = blockIdx.x * 256 + threadIdx.x;
    if (gid < 128) {
        float s = gg[gid] * rsqrtf(vv[gid] + 1e-5f);
        tOut[gid] = (bb[gid] - mm[gid]) * s + be[gid];
    }
    if (gid >= 884736) return;           // 108*2*8*64*8
    int j    = gid & 7;
    int lane = (gid >> 3) & 63;
    int nt   = (gid >> 9) & 7;
    int half = (gid >> 12) & 1;
    int khw  = gid >> 13;
    int co   = nt * 16 + (lane & 15);
    int ci   = half * 32 + (lane >> 4) * 8 + j;
    int kh   = khw / 9, kw = khw - kh * 9;
    float s = gg[co] * rsqrtf(vv[co] + 1e-5f);
    frag[gid] = f2h(W[((co * 64 + ci) * 12 + kh) * 9 + kw] * s);
}

// ---------------------------------------------------------------------------
// FUSED conv1+conv2+conv3+conv4(+pool) per (band, sample), 12 bands x 12 rows
// (R16 was 9x16 at 47.6KB LDS = 3 blocks/CU; this is 38.5KB = 4 blocks/CU).
// Phase 0: fp32 x-slab [17 col][20 row] (T-pad/row-OOB zeroed) + s2 halo zero.
// Phase 1: conv1 scalar fp32, balanced (pos x quad-of-8ch) split (1224 items).
// Phase 2: conv2 (16 rows) -> s2. Phase 3: conv3 (14 rows) -> s3 (aliases s1).
// Phase 4: conv4+pool (12 rows -> 6 pooled) -> global B.
// LDS chunks (16B): s1 = 4q x 307 (18r x 17c), s2 @1228 = 4 x 273 (16r x 17c),
// s3 aliases s1 = 4 x 239 (14r x 17c); sx fp32 @ halves 18560 (340 floats).
// Row mappings transplanted 1:1 from the proven R14 16-row pattern.
// ---------------------------------------------------------------------------
__global__ __launch_bounds__(256) void conv1234f_k(
    const float* __restrict__ x, unsigned short* __restrict__ out,
    const float* __restrict__ wr1, const float* __restrict__ t1v,
    const unsigned short* __restrict__ f2, const unsigned short* __restrict__ f3,
    const unsigned short* __restrict__ f4, const float* __restrict__ t2,
    const float* __restrict__ t3, const float* __restrict__ t4, int c0)
{
    __shared__ __align__(16) unsigned short sm[19240];
    float* sx = (float*)(sm + 18560);                    // [17 col][20 row] fp32
    const int band = blockIdx.x;
    const int nl = blockIdx.y;
    const int n = c0 + nl;
    const int tid = threadIdx.x;
    const int wave = tid >> 6, lane = tid & 63;
    const int m = lane & 15, quad = lane >> 4;
    const int b = n / 108, t = n - b * 108;

    // Phase 0: x-slab staging + s2 halo zero.
    {
        float4* dst = (float4*)sm;
        for (int i = tid; i < 468; i += 256) {
            if (i < 340) {
                int tp = i / 20, fp = i - tp * 20;
                int tt = t - 8 + tp;
                int ff = band * 12 - 4 + fp;
                float v = 0.f;
                if (tt >= 0 && tt < 108 && ff >= 0 && ff < 144)
                    v = x[(b * 108 + tt) * 144 + ff];
                sx[tp * 20 + fp] = v;
            } else {
                int j = i - 340;                 // 4q x 16r x 2cols = 128
                int q = j >> 5, jj = j & 31;
                int rr = jj >> 1, c2 = (jj & 1) * 16;
                dst[1228 + q * 273 + rr * 17 + c2] = (float4){0.f,0.f,0.f,0.f};
            }
        }
    }
    __syncthreads();

    // Phase 1: conv1 scalar fp32, balanced (pos, quad) split -> s1.
    for (int e = tid; e < 1224; e += 256) {
        int pos = e >> 2, qg = e & 3;
        int r = pos / 17, cp = pos - r * 17;
        int gr = band * 12 - 3 + r, gc = cp - 1;
        bool valid = (gr >= 0 && gr < 144 && gc >= 0 && gc < 15);
        float acc1[8];
#pragma unroll
        for (int i = 0; i < 8; ++i) acc1[i] = 0.f;
        if (valid) {
#pragma unroll
            for (int kh = 0; kh < 3; ++kh) {
                int fp = r + kh;
#pragma unroll
                for (int kw = 0; kw < 3; ++kw) {
                    int c = gc + kw - 1;
                    if (c < 0 || c >= 15) continue;   // conv SAME pad
                    float xv = sx[(c + 1) * 20 + fp]; // T-pad zero-filled
                    const float* wp = wr1 + (kh * 3 + kw) * 32 + qg * 8;
                    float4 wA = *(const float4*)(wp);
                    float4 wB = *(const float4*)(wp + 4);
                    acc1[0] = fmaf(xv, wA.x, acc1[0]);
                    acc1[1] = fmaf(xv, wA.y, acc1[1]);
                    acc1[2] = fmaf(xv, wA.z, acc1[2]);
                    acc1[3] = fmaf(xv, wA.w, acc1[3]);
                    acc1[4] = fmaf(xv, wB.x, acc1[4]);
                    acc1[5] = fmaf(xv, wB.y, acc1[5]);
                    acc1[6] = fmaf(xv, wB.z, acc1[6]);
                    acc1[7] = fmaf(xv, wB.w, acc1[7]);
                }
            }
        }
        u16x8 pk;
#pragma unroll
        for (int c8 = 0; c8 < 8; ++c8)
            pk[c8] = valid ? f2h(fmaxf(acc1[c8] + t1v[qg * 8 + c8], 0.f))
                           : (unsigned short)0;
        *(u16x8*)(sm + qg * 2456 + pos * 8) = pk;
    }
    __syncthreads();

    v4f acc[2][4];
    int mt[4], la[4];

    // ---------------- conv2: 16 rows x 15 cols = 240 pos, 15 tiles ----------
#pragma unroll
    for (int wt = 0; wt < 4; ++wt) {
        int tt = wave * 4 + wt; if (tt > 14) tt = 14;
        mt[wt] = tt;
        int p = tt * 16 + m;
        int r = p / 15, c = p - r * 15;
        la[wt] = r * 17 + c;
    }
#pragma unroll
    for (int nt = 0; nt < 2; ++nt)
#pragma unroll
        for (int wt = 0; wt < 4; ++wt) acc[nt][wt] = (v4f){0.f,0.f,0.f,0.f};
#pragma unroll
    for (int khw = 0; khw < 9; ++khw) {
        const int sh = (khw / 3) * 17 + (khw % 3);
        v8h a[4];
#pragma unroll
        for (int wt = 0; wt < 4; ++wt)
            a[wt] = *(const v8h*)(sm + quad * 2456 + (la[wt] + sh) * 8);
#pragma unroll
        for (int nt = 0; nt < 2; ++nt) {
            v8h bb = *(const v8h*)(f2 + (khw * 2 + nt) * 512 + lane * 8);
#pragma unroll
            for (int wt = 0; wt < 4; ++wt)
                acc[nt][wt] = __builtin_amdgcn_mfma_f32_16x16x32_f16(a[wt], bb, acc[nt][wt], 0, 0, 0);
        }
    }
#pragma unroll
    for (int wt = 0; wt < 4; ++wt) {
        const int pb = mt[wt] * 16 + quad * 4;
#pragma unroll
        for (int nt = 0; nt < 2; ++nt) {
            const int co = nt * 16 + m;
            const float tb = t2[co];
            unsigned short* ob = sm + 9824 + (co >> 3) * 2184 + (co & 7);
#pragma unroll
            for (int reg = 0; reg < 4; ++reg) {
                int p = pb + reg;        // < 240 always
                int r = p / 15, c = p - r * 15;
                ob[(r * 17 + c + 1) * 8] = f2h(fmaxf(acc[nt][wt][reg] + tb, 0.f));
            }
        }
    }
    __syncthreads();

    // zero s3 halo cols (s3 aliases dead conv1 slab); disjoint from conv3
    // epilogue stores (cols 1..15), so no extra barrier needed before them.
    if (tid < 112) {
        int q = tid / 28, jj = tid - q * 28;
        int rr = jj >> 1, c2 = (jj & 1) * 16;
        *((float4*)sm + q * 239 + rr * 17 + c2) = (float4){0.f,0.f,0.f,0.f};
    }

    // ---------------- conv3: 14 rows x 15 cols = 210 pos, 14 tiles ----------
#pragma unroll
    for (int wt = 0; wt < 4; ++wt) {
        int tt = wave * 4 + wt; if (tt > 13) tt = 13;
        mt[wt] = tt;
        int p = tt * 16 + m; if (p >= 210) p = 209;
        int r = p / 15, c = p - r * 15;
        la[wt] = r * 17 + c;
    }
#pragma unroll
    for (int nt = 0; nt < 2; ++nt)
#pragma unroll
        for (int wt = 0; wt < 4; ++wt) acc[nt][wt] = (v4f){0.f,0.f,0.f,0.f};
#pragma unroll
    for (int khw = 0; khw < 9; ++khw) {
        const int sh = (khw / 3) * 17 + (khw % 3);
        v8h a[4];
#pragma unroll
        for (int wt = 0; wt < 4; ++wt)
            a[wt] = *(const v8h*)(sm + 9824 + quad * 2184 + (la[wt] + sh) * 8);
#pragma unroll
        for (int nt = 0; nt < 2; ++nt) {
            v8h bb = *(const v8h*)(f3 + (khw * 2 + nt) * 512 + lane * 8);
#pragma unroll
            for (int wt = 0; wt < 4; ++wt)
                acc[nt][wt] = __builtin_amdgcn_mfma_f32_16x16x32_f16(a[wt], bb, acc[nt][wt], 0, 0, 0);
        }
    }
#pragma unroll
    for (int wt = 0; wt < 4; ++wt) {
        const int pb = mt[wt] * 16 + quad * 4;
#pragma unroll
        for (int nt = 0; nt < 2; ++nt) {
            const int co = nt * 16 + m;
            const float tb = t3[co];
            unsigned short* ob = sm + (co >> 3) * 1912 + (co & 7);
#pragma unroll
            for (int reg = 0; reg < 4; ++reg) {
                int p = pb + reg;
                if (p < 210) {
                    int r = p / 15, c = p - r * 15;
                    ob[(r * 17 + c + 1) * 8] = f2h(fmaxf(acc[nt][wt][reg] + tb, 0.f));
                }
            }
        }
    }
    __syncthreads();

    // ---------------- conv4 + pool: 180 pos (pr,w,s ordered), 12 tiles ------
    int mt4[3], la4[3];
#pragma unroll
    for (int wt = 0; wt < 3; ++wt) {
        int tt = wave * 3 + wt;
        mt4[wt] = tt;
        int p = tt * 16 + m; if (p >= 180) p = 179;
        int pr = p / 30, rem = p - pr * 30;
        int w = rem >> 1, r4 = pr * 2 + (rem & 1);
        la4[wt] = r4 * 17 + w;
    }
    v4f acc4[2][3];
#pragma unroll
    for (int nt = 0; nt < 2; ++nt)
#pragma unroll
        for (int wt = 0; wt < 3; ++wt) acc4[nt][wt] = (v4f){0.f,0.f,0.f,0.f};
#pragma unroll
    for (int khw = 0; khw < 9; ++khw) {
        const int sh = (khw / 3) * 17 + (khw % 3);
        v8h a[3];
#pragma unroll
        for (int wt = 0; wt < 3; ++wt)
            a[wt] = *(const v8h*)(sm + quad * 1912 + (la4[wt] + sh) * 8);
#pragma unroll
        for (int nt = 0; nt < 2; ++nt) {
            v8h bb = *(const v8h*)(f4 + (khw * 2 + nt) * 512 + lane * 8);
#pragma unroll
            for (int wt = 0; wt < 3; ++wt)
                acc4[nt][wt] = __builtin_amdgcn_mfma_f32_16x16x32_f16(a[wt], bb, acc4[nt][wt], 0, 0, 0);
        }
    }
    unsigned short* outN = out + (size_t)nl * SLOT;
#pragma unroll
    for (int wt = 0; wt < 3; ++wt) {
        const int pl = mt4[wt] * 16 + quad * 4;          // local p base
        const int pb = band * 180 + pl;                  // global p base
#pragma unroll
        for (int nt = 0; nt < 2; ++nt) {
            const int co = nt * 16 + m;
            const float tb = t4[co];
            unsigned short* ob = outN + (co >> 3) * 9216 + (co & 7);
#pragma unroll
            for (int pi = 0; pi < 2; ++pi) {
                if (pl + pi * 2 < 180) {
                    int pe = pb + pi * 2;
                    int pr = pe / 30, rem = pe - pr * 30, w = rem >> 1;
                    float v0 = fmaxf(acc4[nt][wt][pi * 2] + tb, 0.f);
                    float v1 = fmaxf(acc4[nt][wt][pi * 2 + 1] + tb, 0.f);
                    ob[(pr * 16 + w) * 8] = f2h(fmaxf(v0, v1));
                }
            }
        }
    }
}

// ---------------------------------------------------------------------------
// conv5 MFMA: 32->64ch 3x3 VALID, in [4cg][72][16][8] -> out [8cg][70][16][8].
// ---------------------------------------------------------------------------
__global__ __launch_bounds__(256) void conv5m_k(
    const unsigned short* __restrict__ in, unsigned short* __restrict__ out,
    const unsigned short* __restrict__ frag, const float* __restrict__ tv)
{
    const int n = blockIdx.y;
    const int tid = threadIdx.x;
    const int wave = tid >> 6, lane = tid & 63;
    const int m = lane & 15, quad = lane >> 4;
    const unsigned short* inN = in + (size_t)n * SLOT + quad * 9216;

    int mt[2], a0[2];
#pragma unroll
    for (int wt = 0; wt < 2; ++wt) {
        int t = blockIdx.x * 8 + wave * 2 + wt; if (t > 56) t = 56;
        mt[wt] = t;
        int p = t * 16 + m; if (p > 909) p = 909;
        int r = p / 13, w = p - r * 13;
        a0[wt] = (r * 16 + w) * 8;
    }

    v4f acc[4][2];
#pragma unroll
    for (int nt = 0; nt < 4; ++nt)
#pragma unroll
        for (int wt = 0; wt < 2; ++wt) acc[nt][wt] = (v4f){0.f,0.f,0.f,0.f};

#pragma unroll
    for (int khw = 0; khw < 9; ++khw) {
        const int shift = ((khw / 3) * 16 + (khw % 3)) * 8;
        v8h a[2];
#pragma unroll
        for (int wt = 0; wt < 2; ++wt)
            a[wt] = *(const v8h*)(inN + a0[wt] + shift);
#pragma unroll
        for (int nt = 0; nt < 4; ++nt) {
            v8h b = *(const v8h*)(frag + (khw * 4 + nt) * 512 + lane * 8);
#pragma unroll
            for (int wt = 0; wt < 2; ++wt)
                acc[nt][wt] = __builtin_amdgcn_mfma_f32_16x16x32_f16(a[wt], b, acc[nt][wt], 0, 0, 0);
        }
    }

    unsigned short* outN = out + (size_t)n * SLOT;
#pragma unroll
    for (int wt = 0; wt < 2; ++wt) {
        const int pb = mt[wt] * 16 + quad * 4;
#pragma unroll
        for (int nt = 0; nt < 4; ++nt) {
            const int co = nt * 16 + m;
            const float tb = tv[co];
            unsigned short* ob = outN + (co >> 3) * 8960 + (co & 7);
#pragma unroll
            for (int reg = 0; reg < 4; ++reg) {
                int p = pb + reg;
                if (p < 910) {
                    int r = p / 13, w = p - r * 13;
                    ob[(r * 16 + w) * 8] = f2h(fmaxf(acc[nt][wt][reg] + tb, 0.f));
                }
            }
        }
    }
}

// ---------------------------------------------------------------------------
// conv6 MFMA (+fused pool) -> c6 [8cg][34r][11c][8], row stride 11.
// ---------------------------------------------------------------------------
__global__ __launch_bounds__(256) void conv6m_k(
    const unsigned short* __restrict__ in, unsigned short* __restrict__ c6,
    const unsigned short* __restrict__ frag, const float* __restrict__ tv)
{
    const int n = blockIdx.y;
    const int tid = threadIdx.x;
    const int wave = tid >> 6, lane = tid & 63;
    const int m = lane & 15, quad = lane >> 4;
    const unsigned short* inN = in + (size_t)n * SLOT;

    int mt[2], a0[2];
#pragma unroll
    for (int wt = 0; wt < 2; ++wt) {
        int t = blockIdx.x * 8 + wave * 2 + wt; if (t > 46) t = 46;
        mt[wt] = t;
        int p = t * 16 + m; if (p > 747) p = 747;
        int pr = p / 22, rem = p - pr * 22;
        int w = rem >> 1, r = pr * 2 + (rem & 1);
        a0[wt] = (r * 16 + w) * 8;
    }

    v4f acc[4][2];
#pragma unroll
    for (int nt = 0; nt < 4; ++nt)
#pragma unroll
        for (int wt = 0; wt < 2; ++wt) acc[nt][wt] = (v4f){0.f,0.f,0.f,0.f};

#pragma unroll
    for (int khw = 0; khw < 9; ++khw) {
        const int shift = ((khw / 3) * 16 + (khw % 3)) * 8;
#pragma unroll
        for (int half = 0; half < 2; ++half) {
            const unsigned short* ip = inN + (half * 4 + quad) * 8960 + shift;
            v8h a[2];
#pragma unroll
            for (int wt = 0; wt < 2; ++wt)
                a[wt] = *(const v8h*)(ip + a0[wt]);
#pragma unroll
            for (int nt = 0; nt < 4; ++nt) {
                v8h b = *(const v8h*)(frag + ((khw * 2 + half) * 4 + nt) * 512 + lane * 8);
#pragma unroll
                for (int wt = 0; wt < 2; ++wt)
                    acc[nt][wt] = __builtin_amdgcn_mfma_f32_16x16x32_f16(a[wt], b, acc[nt][wt], 0, 0, 0);
            }
        }
    }

    unsigned short* outN = c6 + (size_t)n * C6N;
#pragma unroll
    for (int wt = 0; wt < 2; ++wt) {
        const int pb = mt[wt] * 16 + quad * 4;
#pragma unroll
        for (int nt = 0; nt < 4; ++nt) {
            const int co = nt * 16 + m;
            const float tb = tv[co];
            unsigned short* ob = outN + (co >> 3) * 2992 + (co & 7);
#pragma unroll
            for (int pi = 0; pi < 2; ++pi) {
                int pe = pb + pi * 2;
                if (pe < 748) {
                    int pr = pe / 22, rem = pe - pr * 22, w = rem >> 1;
                    float v0 = fmaxf(acc[nt][wt][pi * 2] + tb, 0.f);
                    float v1 = fmaxf(acc[nt][wt][pi * 2 + 1] + tb, 0.f);
                    ob[(pr * 11 + w) * 8] = f2h(fmaxf(v0, v1));
                }
            }
        }
    }
}

// ---------------------------------------------------------------------------
// Conv7 MFMA GEMM — R12-measured-best config (48 VGPR, 42% occ, 196us):
// LDS 443 quad stride / 13 row stride; staging remaps from stride-11 c6.
// ---------------------------------------------------------------------------
__global__ __launch_bounds__(256) void conv7mfma_k(
    const unsigned short* __restrict__ c6, float* __restrict__ pooled,
    const unsigned short* __restrict__ frag7, const float* __restrict__ tv)
{
    __shared__ __align__(16) unsigned short sA[14176];  // 4 x 443 x 8
    const int n = blockIdx.x;
    const int tid = threadIdx.x;
    const int wave = tid >> 6;
    const int lane = tid & 63;
    const int m = lane & 15;
    const int quad = lane >> 4;

    int pm[5];
#pragma unroll
    for (int mt = 0; mt < 5; ++mt) {
        int p = mt * 16 + m;
        if (p >= 69) p = 0;
        pm[mt] = (p / 3) * 13 + (p % 3);
    }

    v4f acc[2][5];
#pragma unroll
    for (int t = 0; t < 2; ++t)
#pragma unroll
        for (int mt = 0; mt < 5; ++mt)
            acc[t][mt] = (v4f){0.f, 0.f, 0.f, 0.f};

    for (int half = 0; half < 2; ++half) {
        __syncthreads();
        {
            const float4* src = (const float4*)(c6 + (size_t)n * C6N + half * 11968);
            float4* dst = (float4*)sA;
            for (int i = tid; i < 1496; i += 256) {
                int q = i / 374, pos = i - q * 374;
                int h = pos / 11, w = pos - h * 11;
                dst[q * 443 + h * 13 + w] = src[i];
            }
        }
        __syncthreads();
        for (int khw = 0; khw < 108; ++khw) {
            const int off = (khw / 9) * 13 + (khw % 9);
            v8h a[5];
#pragma unroll
            for (int mt = 0; mt < 5; ++mt)
                a[mt] = *(const v8h*)(sA + (quad * 443 + pm[mt] + off) * 8);
            const unsigned short* bp = frag7
                + ((size_t)(khw * 2 + half) * 8) * 512 + lane * 8;
#pragma unroll
            for (int t = 0; t < 2; ++t) {
                const int nt = wave + t * 4;
                v8h b = *(const v8h*)(bp + nt * 512);
#pragma unroll
                for (int mt = 0; mt < 5; ++mt)
                    acc[t][mt] = __builtin_amdgcn_mfma_f32_16x16x32_f16(
                        a[mt], b, acc[t][mt], 0, 0, 0);
            }
        }
    }

    float s[2] = {0.f, 0.f};
#pragma unroll
    for (int t = 0; t < 2; ++t) {
        const float tb = tv[(wave + t * 4) * 16 + m];
#pragma unroll
        for (int mt = 0; mt < 5; ++mt) {
#pragma unroll
            for (int rr = 0; rr < 4; ++rr) {
                int p = mt * 16 + quad * 4 + rr;
                if (p < 69) s[t] += fmaxf(acc[t][mt][rr] + tb, 0.f);
            }
        }
    }
#pragma unroll
    for (int t = 0; t < 2; ++t) {
        s[t] += __shfl_xor(s[t], 16);
        s[t] += __shfl_xor(s[t], 32);
    }
    if (lane < 16) {
#pragma unroll
        for (int t = 0; t < 2; ++t)
            pooled[(size_t)n * 128 + (wave + t * 4) * 16 + lane] = s[t] * (1.f / 69.f);
    }
}

// ---------------------------------------------------------------------------
// logits = b8 + W8(25x128) . pooled
// ---------------------------------------------------------------------------
__global__ void logits_k(const float* __restrict__ pooled, const float* __restrict__ W8,
                         const float* __restrict__ b8, float* __restrict__ outg,
                         int total)
{
    int gid = blockIdx.x * 256 + threadIdx.x;
    if (gid >= total * 25) return;
    int nl = gid / 25, c = gid - nl * 25;
    const float* pp = pooled + (size_t)nl * 128;
    const float* wp = W8 + c * 128;
    float s = b8[c];
#pragma unroll
    for (int ci = 0; ci < 128; ci += 4) {
        float4 wv = *(const float4*)(wp + ci);
        float4 pv = *(const float4*)(pp + ci);
        s = fmaf(wv.x, pv.x, s);
        s = fmaf(wv.y, pv.y, s);
        s = fmaf(wv.z, pv.z, s);
        s = fmaf(wv.w, pv.w, s);
    }
    outg[(size_t)nl * 25 + c] = s;
}

// ---------------------------------------------------------------------------
extern "C" void kernel_launch(void* const* d_in, const int* in_sizes, int n_in,
                              void* d_out, int out_size, void* d_ws, size_t ws_size,
                              hipStream_t stream)
{
    const float* x = (const float*)d_in[0];
    const float* Wl[8]; const float* bl[8]; const float* gl[8];
    const float* bel[8]; const float* ml[8]; const float* vl[8];
    for (int i = 1; i <= 7; ++i) {
        int o = 2 + (i - 1) * 6;
        Wl[i]  = (const float*)d_in[o + 0];
        bl[i]  = (const float*)d_in[o + 1];
        gl[i]  = (const float*)d_in[o + 2];
        bel[i] = (const float*)d_in[o + 3];
        ml[i]  = (const float*)d_in[o + 4];
        vl[i]  = (const float*)d_in[o + 5];
    }
    const float* W8 = (const float*)d_in[44];
    const float* b8 = (const float*)d_in[45];
    float* ws = (float*)d_ws;

    // Workspace layout (float offsets); all 16B aligned.
    float* wr1 = ws + 0;        float* t1 = ws + 288;
    unsigned short* f2b = (unsigned short*)(ws + 320);
    float* t2 = ws + 4928;
    unsigned short* f3b = (unsigned short*)(ws + 4960);
    float* t3 = ws + 9568;
    unsigned short* f4b = (unsigned short*)(ws + 9600);
    float* t4 = ws + 14208;
    unsigned short* f5b = (unsigned short*)(ws + 14240);
    float* t5 = ws + 23456;
    unsigned short* f6b = (unsigned short*)(ws + 23520);
    float* t6 = ws + 41952;
    unsigned short* f7b = (unsigned short*)(ws + 42016);
    float* t7 = ws + 484384;
    const size_t WFL = 484512;

    // Persistent: c6 ([n][8cg][34r][11c][8] fp16) + pooled (fp32).
    unsigned short* c6buf = (unsigned short*)(ws + WFL);
    const size_t C6FL = (size_t)1728 * C6N / 2;
    float* pooled = ws + WFL + C6FL;
    const size_t FIXED = WFL + C6FL + (size_t)1728 * 128;

    size_t avail_fl = ws_size / 4;
    size_t buf_halves = (avail_fl > FIXED) ? (avail_fl - FIXED) * 2 : 0;
    int Cs = (int)(buf_halves / (size_t)SLOT);
    if (Cs < 1) Cs = 1;
    if (Cs > 1728) Cs = 1728;
    unsigned short* bufA = (unsigned short*)(ws + FIXED);   // region A (off 0)
    unsigned short* bufB = bufA + TA;                        // region B (off TA)

    auto g1 = [](int t) { return (t + 255) / 256; };

    // Weight repacks (once per call)
    repack_k<<<g1(288), 256, 0, stream>>>(Wl[1], bl[1], gl[1], bel[1], ml[1], vl[1], wr1, t1, 1, 9, 32);
    repack_mfma_k<<<g1(9216),  256, 0, stream>>>(Wl[2], bl[2], gl[2], bel[2], ml[2], vl[2], f2b, t2, 32, 2, 1);
    repack_mfma_k<<<g1(9216),  256, 0, stream>>>(Wl[3], bl[3], gl[3], bel[3], ml[3], vl[3], f3b, t3, 32, 2, 1);
    repack_mfma_k<<<g1(9216),  256, 0, stream>>>(Wl[4], bl[4], gl[4], bel[4], ml[4], vl[4], f4b, t4, 32, 2, 1);
    repack_mfma_k<<<g1(18432), 256, 0, stream>>>(Wl[5], bl[5], gl[5], bel[5], ml[5], vl[5], f5b, t5, 32, 4, 1);
    repack_mfma_k<<<g1(36864), 256, 0, stream>>>(Wl[6], bl[6], gl[6], bel[6], ml[6], vl[6], f6b, t6, 64, 4, 2);
    repack7_k<<<g1(884736), 256, 0, stream>>>(Wl[7], bl[7], gl[7], bel[7], ml[7], vl[7], f7b, t7);

    // Stage 1 (chunked, tight layouts):
    // fused conv1/2/3/4 x->B (12 bands), conv5 B->A, conv6 A->c6
    for (int c0 = 0; c0 < 1728; c0 += Cs) {
        int cn = (1728 - c0 < Cs) ? (1728 - c0) : Cs;
        conv1234f_k<<<dim3(12, cn), 256, 0, stream>>>(x, bufB, wr1, t1,
                                                      f2b, f3b, f4b, t2, t3, t4, c0);
        conv5m_k<<<dim3(8, cn), 256, 0, stream>>>(bufB, bufA, f5b, t5);
        conv6m_k<<<dim3(6, cn), 256, 0, stream>>>(bufA, c6buf + (size_t)c0 * C6N, f6b, t6);
    }

    // Stage 2: conv7 MFMA (+bias+relu+mean) over all samples, then logits.
    conv7mfma_k<<<1728, 256, 0, stream>>>(c6buf, pooled, f7b, t7);
    logits_k<<<g1(1728 * 25), 256, 0, stream>>>(pooled, W8, b8, (float*)d_out, 1728);
}

// Round 18
// 1238.169 us; speedup vs baseline: 1.0607x; 1.0607x over previous
//
#include <hip/hip_runtime.h>
#include <hip/hip_bf16.h>
#include <hip/hip_fp16.h>

// Tight stage-1 activations. Per-sample slot = region A + region B (halves).
// A: conv5 out [8cg][70][16][8]=71680. B: conv4-pool out [4cg][72][16][8]=36864.
// conv1/conv2/conv3 outs live in LDS only (fused band kernel).
#define TA 71680
#define SLOT 108544
// conv6 output halves per sample: [8 cg][34 rows][11 cols][8 ci], row stride 11
#define C6N 23936

typedef _Float16 v8h __attribute__((ext_vector_type(8)));
typedef float v4f __attribute__((ext_vector_type(4)));
typedef unsigned short u16x8 __attribute__((ext_vector_type(8)));

__device__ inline float h2f(unsigned short u) {
    union { unsigned short s; _Float16 h; } v; v.s = u; return (float)v.h;
}
__device__ inline unsigned short f2h(float f) {
    union { unsigned short s; _Float16 h; } v; v.h = (_Float16)f; return v.s;
}

// ---------------------------------------------------------------------------
// conv1 weight repack (fp32): [co][1][kh][kw] -> [k][co], BN folded; emits t.
// ---------------------------------------------------------------------------
__global__ void repack_k(const float* __restrict__ W, const float* __restrict__ bb,
                         const float* __restrict__ gg, const float* __restrict__ be,
                         const float* __restrict__ mm, const float* __restrict__ vv,
                         float* __restrict__ wOut, float* __restrict__ tOut,
                         int CIN, int KHW, int COUT)
{
    int gid = blockIdx.x * 256 + threadIdx.x;
    if (gid < COUT) {
        float s = gg[gid] * rsqrtf(vv[gid] + 1e-5f);
        tOut[gid] = (bb[gid] - mm[gid]) * s + be[gid];
    }
    int tot = CIN * KHW * COUT;
    if (gid >= tot) return;
    int co = gid % COUT;
    int rest = gid / COUT;
    int k = rest % KHW;
    int ci = rest / KHW;
    float s = gg[co] * rsqrtf(vv[co] + 1e-5f);
    wOut[gid] = W[(co * CIN + ci) * KHW + k] * s;
}

// ---------------------------------------------------------------------------
// MFMA B-fragment repack for 3x3 layers (conv2..conv6), fp16.
// ---------------------------------------------------------------------------
__global__ void repack_mfma_k(const float* __restrict__ W, const float* __restrict__ bb,
                              const float* __restrict__ gg, const float* __restrict__ be,
                              const float* __restrict__ mm, const float* __restrict__ vv,
                              unsigned short* __restrict__ frag, float* __restrict__ tOut,
                              int CIN, int NT, int HALVES)
{
    int gid = blockIdx.x * 256 + threadIdx.x;
    int COUT = NT * 16;
    if (gid < COUT) {
        float s = gg[gid] * rsqrtf(vv[gid] + 1e-5f);
        tOut[gid] = (bb[gid] - mm[gid]) * s + be[gid];
    }
    int tot = 9 * HALVES * NT * 512;
    if (gid >= tot) return;
    int j    = gid & 7;
    int lane = (gid >> 3) & 63;
    int nt   = (gid >> 9) % NT;
    int rest = (gid >> 9) / NT;
    int half = rest % HALVES;
    int khw  = rest / HALVES;
    int ci   = half * 32 + (lane >> 4) * 8 + j;
    int co   = nt * 16 + (lane & 15);
    int kh   = khw / 3, kw = khw % 3;
    float s = gg[co] * rsqrtf(vv[co] + 1e-5f);
    frag[gid] = f2h(W[((co * CIN + ci) * 3 + kh) * 3 + kw] * s);
}

// ---------------------------------------------------------------------------
// Conv7 weight repack into MFMA B-fragment order (12x9 kernel), fp16.
// ---------------------------------------------------------------------------
__global__ void repack7_k(const float* __restrict__ W, const float* __restrict__ bb,
                          const float* __restrict__ gg, const float* __restrict__ be,
                          const float* __restrict__ mm, const float* __restrict__ vv,
                          unsigned short* __restrict__ frag, float* __restrict__ tOut)
{
    int gid = blockIdx.x * 256 + threadIdx.x;
    if (gid < 128) {
        float s = gg[gid] * rsqrtf(vv[gid] + 1e-5f);
        tOut[gid] = (bb[gid] - mm[gid]) * s + be[gid];
    }
    if (gid >= 884736) return;           // 108*2*8*64*8
    int j    = gid & 7;
    int lane = (gid >> 3) & 63;
    int nt   = (gid >> 9) & 7;
    int half = (gid >> 12) & 1;
    int khw  = gid >> 13;
    int co   = nt * 16 + (lane & 15);
    int ci   = half * 32 + (lane >> 4) * 8 + j;
    int kh   = khw / 9, kw = khw - kh * 9;
    float s = gg[co] * rsqrtf(vv[co] + 1e-5f);
    frag[gid] = f2h(W[((co * 64 + ci) * 12 + kh) * 9 + kw] * s);
}

// ---------------------------------------------------------------------------
// FUSED conv1+conv2+conv3+conv4(+pool) per (band, sample) — R14-measured-best
// geometry (9 bands x 16 out rows; the R17 12-band variant raised occupancy
// but lost 33% to per-block overhead). Single delta vs R14: conv1 phase uses
// the balanced (pos x quad-of-8ch) split (1496 items, acc[8]) -- removes the
// 2x wave imbalance of the acc[32] form; verified correct in R17.
// LDS (halves): s1 = 4q x 375c @0, s2 = 4 x 341c @12000, s3 aliases s1
// (4 x 307c), sx fp32 x-slab @22912 ([17 col][24 row]). 47.5 KB -> 3 blk/CU.
// ---------------------------------------------------------------------------
__global__ __launch_bounds__(256) void conv1234f_k(
    const float* __restrict__ x, unsigned short* __restrict__ out,
    const float* __restrict__ wr1, const float* __restrict__ t1v,
    const unsigned short* __restrict__ f2, const unsigned short* __restrict__ f3,
    const unsigned short* __restrict__ f4, const float* __restrict__ t2,
    const float* __restrict__ t3, const float* __restrict__ t4, int c0)
{
    __shared__ __align__(16) unsigned short sm[23728];   // slabs + sx
    float* sx = (float*)(sm + 22912);                    // [17 col][24 row] fp32
    const int band = blockIdx.x;
    const int nl = blockIdx.y;
    const int n = c0 + nl;
    const int tid = threadIdx.x;
    const int wave = tid >> 6, lane = tid & 63;
    const int m = lane & 15, quad = lane >> 4;
    const int b = n / 108, t = n - b * 108;

    // Phase 0: x-slab staging + s2 halo zero.
    {
        float4* dst = (float4*)sm;
        for (int i = tid; i < 568; i += 256) {
            if (i < 408) {
                int tp = i / 24, fp = i - tp * 24;
                int tt = t - 8 + tp;
                int ff = band * 16 - 4 + fp;
                float v = 0.f;
                if (tt >= 0 && tt < 108 && ff >= 0 && ff < 144)
                    v = x[(b * 108 + tt) * 144 + ff];
                sx[tp * 24 + fp] = v;
            } else {
                int j = i - 408;                 // 4q x 20r x 2cols = 160
                int q = j / 40, jj = j - q * 40;
                int rr = jj >> 1, c2 = (jj & 1) * 16;
                dst[1500 + q * 341 + rr * 17 + c2] = (float4){0.f,0.f,0.f,0.f};
            }
        }
    }
    __syncthreads();

    // Phase 1: conv1 scalar fp32, balanced (pos, qg) split -> s1 [4q][374][8].
    for (int e = tid; e < 1496; e += 256) {
        int pos = e >> 2, qg = e & 3;
        int r = pos / 17, cp = pos - r * 17;
        int gr = band * 16 - 3 + r, gc = cp - 1;
        bool valid = (gr >= 0 && gr < 144 && gc >= 0 && gc < 15);
        float acc1[8];
#pragma unroll
        for (int i = 0; i < 8; ++i) acc1[i] = 0.f;
        if (valid) {
#pragma unroll
            for (int kh = 0; kh < 3; ++kh) {
                int fp = r + kh;
#pragma unroll
                for (int kw = 0; kw < 3; ++kw) {
                    int c = gc + kw - 1;
                    if (c < 0 || c >= 15) continue;   // conv SAME pad
                    float xv = sx[(c + 1) * 24 + fp]; // T-pad zero-filled
                    const float* wp = wr1 + (kh * 3 + kw) * 32 + qg * 8;
                    float4 wA = *(const float4*)(wp);
                    float4 wB = *(const float4*)(wp + 4);
                    acc1[0] = fmaf(xv, wA.x, acc1[0]);
                    acc1[1] = fmaf(xv, wA.y, acc1[1]);
                    acc1[2] = fmaf(xv, wA.z, acc1[2]);
                    acc1[3] = fmaf(xv, wA.w, acc1[3]);
                    acc1[4] = fmaf(xv, wB.x, acc1[4]);
                    acc1[5] = fmaf(xv, wB.y, acc1[5]);
                    acc1[6] = fmaf(xv, wB.z, acc1[6]);
                    acc1[7] = fmaf(xv, wB.w, acc1[7]);
                }
            }
        }
        u16x8 pk;
#pragma unroll
        for (int c8 = 0; c8 < 8; ++c8)
            pk[c8] = valid ? f2h(fmaxf(acc1[c8] + t1v[qg * 8 + c8], 0.f))
                           : (unsigned short)0;
        *(u16x8*)(sm + qg * 3000 + pos * 8) = pk;
    }
    __syncthreads();

    v4f acc[2][5];
    int mt[5], la[5];

    // ---------------- conv2: 20 rows x 15 cols = 300 pos, 19 tiles ----------
#pragma unroll
    for (int wt = 0; wt < 5; ++wt) {
        int tt = wave * 5 + wt; if (tt > 18) tt = 18;
        mt[wt] = tt;
        int p = tt * 16 + m; if (p >= 300) p = 299;
        int r = p / 15, c = p - r * 15;
        la[wt] = r * 17 + c;
    }
#pragma unroll
    for (int nt = 0; nt < 2; ++nt)
#pragma unroll
        for (int wt = 0; wt < 5; ++wt) acc[nt][wt] = (v4f){0.f,0.f,0.f,0.f};
#pragma unroll
    for (int khw = 0; khw < 9; ++khw) {
        const int sh = (khw / 3) * 17 + (khw % 3);
        v8h a[5];
#pragma unroll
        for (int wt = 0; wt < 5; ++wt)
            a[wt] = *(const v8h*)(sm + quad * 3000 + (la[wt] + sh) * 8);
#pragma unroll
        for (int nt = 0; nt < 2; ++nt) {
            v8h bb = *(const v8h*)(f2 + (khw * 2 + nt) * 512 + lane * 8);
#pragma unroll
            for (int wt = 0; wt < 5; ++wt)
                acc[nt][wt] = __builtin_amdgcn_mfma_f32_16x16x32_f16(a[wt], bb, acc[nt][wt], 0, 0, 0);
        }
    }
#pragma unroll
    for (int wt = 0; wt < 5; ++wt) {
        const int pb = mt[wt] * 16 + quad * 4;
#pragma unroll
        for (int nt = 0; nt < 2; ++nt) {
            const int co = nt * 16 + m;
            const float tb = t2[co];
            unsigned short* ob = sm + 12000 + (co >> 3) * 2728 + (co & 7);
#pragma unroll
            for (int reg = 0; reg < 4; ++reg) {
                int p = pb + reg;
                if (p < 300) {
                    int r = p / 15, c = p - r * 15;
                    ob[(r * 17 + c + 1) * 8] = f2h(fmaxf(acc[nt][wt][reg] + tb, 0.f));
                }
            }
        }
    }
    __syncthreads();

    // zero s3 halo cols (s3 aliases dead conv1 slab)
    if (tid < 144) {
        int q = tid / 36, jj = tid - q * 36;
        int rr = jj >> 1, c2 = (jj & 1) * 16;
        *((float4*)sm + q * 307 + rr * 17 + c2) = (float4){0.f,0.f,0.f,0.f};
    }

    // ---------------- conv3: 18 rows x 15 cols = 270 pos, 17 tiles ----------
#pragma unroll
    for (int wt = 0; wt < 5; ++wt) {
        int tt = wave * 5 + wt; if (tt > 16) tt = 16;
        mt[wt] = tt;
        int p = tt * 16 + m; if (p >= 270) p = 269;
        int r = p / 15, c = p - r * 15;
        la[wt] = r * 17 + c;
    }
#pragma unroll
    for (int nt = 0; nt < 2; ++nt)
#pragma unroll
        for (int wt = 0; wt < 5; ++wt) acc[nt][wt] = (v4f){0.f,0.f,0.f,0.f};
#pragma unroll
    for (int khw = 0; khw < 9; ++khw) {
        const int sh = (khw / 3) * 17 + (khw % 3);
        v8h a[5];
#pragma unroll
        for (int wt = 0; wt < 5; ++wt)
            a[wt] = *(const v8h*)(sm + 12000 + quad * 2728 + (la[wt] + sh) * 8);
#pragma unroll
        for (int nt = 0; nt < 2; ++nt) {
            v8h bb = *(const v8h*)(f3 + (khw * 2 + nt) * 512 + lane * 8);
#pragma unroll
            for (int wt = 0; wt < 5; ++wt)
                acc[nt][wt] = __builtin_amdgcn_mfma_f32_16x16x32_f16(a[wt], bb, acc[nt][wt], 0, 0, 0);
        }
    }
#pragma unroll
    for (int wt = 0; wt < 5; ++wt) {
        const int pb = mt[wt] * 16 + quad * 4;
#pragma unroll
        for (int nt = 0; nt < 2; ++nt) {
            const int co = nt * 16 + m;
            const float tb = t3[co];
            unsigned short* ob = sm + (co >> 3) * 2456 + (co & 7);
#pragma unroll
            for (int reg = 0; reg < 4; ++reg) {
                int p = pb + reg;
                if (p < 270) {
                    int r = p / 15, c = p - r * 15;
                    ob[(r * 17 + c + 1) * 8] = f2h(fmaxf(acc[nt][wt][reg] + tb, 0.f));
                }
            }
        }
    }
    __syncthreads();

    // ---------------- conv4 + pool: 240 pos (pr,w,s ordered), 15 tiles ------
    int mt4[4], la4[4];
#pragma unroll
    for (int wt = 0; wt < 4; ++wt) {
        int tt = wave * 4 + wt; if (tt > 14) tt = 14;
        mt4[wt] = tt;
        int p = tt * 16 + m;
        int pr = p / 30, rem = p - pr * 30;
        int w = rem >> 1, r4 = pr * 2 + (rem & 1);
        la4[wt] = r4 * 17 + w;
    }
    v4f acc4[2][4];
#pragma unroll
    for (int nt = 0; nt < 2; ++nt)
#pragma unroll
        for (int wt = 0; wt < 4; ++wt) acc4[nt][wt] = (v4f){0.f,0.f,0.f,0.f};
#pragma unroll
    for (int khw = 0; khw < 9; ++khw) {
        const int sh = (khw / 3) * 17 + (khw % 3);
        v8h a[4];
#pragma unroll
        for (int wt = 0; wt < 4; ++wt)
            a[wt] = *(const v8h*)(sm + quad * 2456 + (la4[wt] + sh) * 8);
#pragma unroll
        for (int nt = 0; nt < 2; ++nt) {
            v8h bb = *(const v8h*)(f4 + (khw * 2 + nt) * 512 + lane * 8);
#pragma unroll
            for (int wt = 0; wt < 4; ++wt)
                acc4[nt][wt] = __builtin_amdgcn_mfma_f32_16x16x32_f16(a[wt], bb, acc4[nt][wt], 0, 0, 0);
        }
    }
    unsigned short* outN = out + (size_t)nl * SLOT;
#pragma unroll
    for (int wt = 0; wt < 4; ++wt) {
        const int pb = band * 240 + mt4[wt] * 16 + quad * 4;
#pragma unroll
        for (int nt = 0; nt < 2; ++nt) {
            const int co = nt * 16 + m;
            const float tb = t4[co];
            unsigned short* ob = outN + (co >> 3) * 9216 + (co & 7);
#pragma unroll
            for (int pi = 0; pi < 2; ++pi) {
                int pe = pb + pi * 2;
                int pr = pe / 30, rem = pe - pr * 30, w = rem >> 1;
                float v0 = fmaxf(acc4[nt][wt][pi * 2] + tb, 0.f);
                float v1 = fmaxf(acc4[nt][wt][pi * 2 + 1] + tb, 0.f);
                ob[(pr * 16 + w) * 8] = f2h(fmaxf(v0, v1));
            }
        }
    }
}

// ---------------------------------------------------------------------------
// conv5 MFMA: 32->64ch 3x3 VALID, in [4cg][72][16][8] -> out [8cg][70][16][8].
// ---------------------------------------------------------------------------
__global__ __launch_bounds__(256) void conv5m_k(
    const unsigned short* __restrict__ in, unsigned short* __restrict__ out,
    const unsigned short* __restrict__ frag, const float* __restrict__ tv)
{
    const int n = blockIdx.y;
    const int tid = threadIdx.x;
    const int wave = tid >> 6, lane = tid & 63;
    const int m = lane & 15, quad = lane >> 4;
    const unsigned short* inN = in + (size_t)n * SLOT + quad * 9216;

    int mt[2], a0[2];
#pragma unroll
    for (int wt = 0; wt < 2; ++wt) {
        int t = blockIdx.x * 8 + wave * 2 + wt; if (t > 56) t = 56;
        mt[wt] = t;
        int p = t * 16 + m; if (p > 909) p = 909;
        int r = p / 13, w = p - r * 13;
        a0[wt] = (r * 16 + w) * 8;
    }

    v4f acc[4][2];
#pragma unroll
    for (int nt = 0; nt < 4; ++nt)
#pragma unroll
        for (int wt = 0; wt < 2; ++wt) acc[nt][wt] = (v4f){0.f,0.f,0.f,0.f};

#pragma unroll
    for (int khw = 0; khw < 9; ++khw) {
        const int shift = ((khw / 3) * 16 + (khw % 3)) * 8;
        v8h a[2];
#pragma unroll
        for (int wt = 0; wt < 2; ++wt)
            a[wt] = *(const v8h*)(inN + a0[wt] + shift);
#pragma unroll
        for (int nt = 0; nt < 4; ++nt) {
            v8h b = *(const v8h*)(frag + (khw * 4 + nt) * 512 + lane * 8);
#pragma unroll
            for (int wt = 0; wt < 2; ++wt)
                acc[nt][wt] = __builtin_amdgcn_mfma_f32_16x16x32_f16(a[wt], b, acc[nt][wt], 0, 0, 0);
        }
    }

    unsigned short* outN = out + (size_t)n * SLOT;
#pragma unroll
    for (int wt = 0; wt < 2; ++wt) {
        const int pb = mt[wt] * 16 + quad * 4;
#pragma unroll
        for (int nt = 0; nt < 4; ++nt) {
            const int co = nt * 16 + m;
            const float tb = tv[co];
            unsigned short* ob = outN + (co >> 3) * 8960 + (co & 7);
#pragma unroll
            for (int reg = 0; reg < 4; ++reg) {
                int p = pb + reg;
                if (p < 910) {
                    int r = p / 13, w = p - r * 13;
                    ob[(r * 16 + w) * 8] = f2h(fmaxf(acc[nt][wt][reg] + tb, 0.f));
                }
            }
        }
    }
}

// ---------------------------------------------------------------------------
// conv6 MFMA (+fused pool) -> c6 [8cg][34r][11c][8], row stride 11.
// ---------------------------------------------------------------------------
__global__ __launch_bounds__(256) void conv6m_k(
    const unsigned short* __restrict__ in, unsigned short* __restrict__ c6,
    const unsigned short* __restrict__ frag, const float* __restrict__ tv)
{
    const int n = blockIdx.y;
    const int tid = threadIdx.x;
    const int wave = tid >> 6, lane = tid & 63;
    const int m = lane & 15, quad = lane >> 4;
    const unsigned short* inN = in + (size_t)n * SLOT;

    int mt[2], a0[2];
#pragma unroll
    for (int wt = 0; wt < 2; ++wt) {
        int t = blockIdx.x * 8 + wave * 2 + wt; if (t > 46) t = 46;
        mt[wt] = t;
        int p = t * 16 + m; if (p > 747) p = 747;
        int pr = p / 22, rem = p - pr * 22;
        int w = rem >> 1, r = pr * 2 + (rem & 1);
        a0[wt] = (r * 16 + w) * 8;
    }

    v4f acc[4][2];
#pragma unroll
    for (int nt = 0; nt < 4; ++nt)
#pragma unroll
        for (int wt = 0; wt < 2; ++wt) acc[nt][wt] = (v4f){0.f,0.f,0.f,0.f};

#pragma unroll
    for (int khw = 0; khw < 9; ++khw) {
        const int shift = ((khw / 3) * 16 + (khw % 3)) * 8;
#pragma unroll
        for (int half = 0; half < 2; ++half) {
            const unsigned short* ip = inN + (half * 4 + quad) * 8960 + shift;
            v8h a[2];
#pragma unroll
            for (int wt = 0; wt < 2; ++wt)
                a[wt] = *(const v8h*)(ip + a0[wt]);
#pragma unroll
            for (int nt = 0; nt < 4; ++nt) {
                v8h b = *(const v8h*)(frag + ((khw * 2 + half) * 4 + nt) * 512 + lane * 8);
#pragma unroll
                for (int wt = 0; wt < 2; ++wt)
                    acc[nt][wt] = __builtin_amdgcn_mfma_f32_16x16x32_f16(a[wt], b, acc[nt][wt], 0, 0, 0);
            }
        }
    }

    unsigned short* outN = c6 + (size_t)n * C6N;
#pragma unroll
    for (int wt = 0; wt < 2; ++wt) {
        const int pb = mt[wt] * 16 + quad * 4;
#pragma unroll
        for (int nt = 0; nt < 4; ++nt) {
            const int co = nt * 16 + m;
            const float tb = tv[co];
            unsigned short* ob = outN + (co >> 3) * 2992 + (co & 7);
#pragma unroll
            for (int pi = 0; pi < 2; ++pi) {
                int pe = pb + pi * 2;
                if (pe < 748) {
                    int pr = pe / 22, rem = pe - pr * 22, w = rem >> 1;
                    float v0 = fmaxf(acc[nt][wt][pi * 2] + tb, 0.f);
                    float v1 = fmaxf(acc[nt][wt][pi * 2 + 1] + tb, 0.f);
                    ob[(pr * 11 + w) * 8] = f2h(fmaxf(v0, v1));
                }
            }
        }
    }
}

// ---------------------------------------------------------------------------
// Conv7 MFMA GEMM — R12-measured-best config (48 VGPR, 42% occ, 196us):
// LDS 443 quad stride / 13 row stride; staging remaps from stride-11 c6.
// ---------------------------------------------------------------------------
__global__ __launch_bounds__(256) void conv7mfma_k(
    const unsigned short* __restrict__ c6, float* __restrict__ pooled,
    const unsigned short* __restrict__ frag7, const float* __restrict__ tv)
{
    __shared__ __align__(16) unsigned short sA[14176];  // 4 x 443 x 8
    const int n = blockIdx.x;
    const int tid = threadIdx.x;
    const int wave = tid >> 6;
    const int lane = tid & 63;
    const int m = lane & 15;
    const int quad = lane >> 4;

    int pm[5];
#pragma unroll
    for (int mt = 0; mt < 5; ++mt) {
        int p = mt * 16 + m;
        if (p >= 69) p = 0;
        pm[mt] = (p / 3) * 13 + (p % 3);
    }

    v4f acc[2][5];
#pragma unroll
    for (int t = 0; t < 2; ++t)
#pragma unroll
        for (int mt = 0; mt < 5; ++mt)
            acc[t][mt] = (v4f){0.f, 0.f, 0.f, 0.f};

    for (int half = 0; half < 2; ++half) {
        __syncthreads();
        {
            const float4* src = (const float4*)(c6 + (size_t)n * C6N + half * 11968);
            float4* dst = (float4*)sA;
            for (int i = tid; i < 1496; i += 256) {
                int q = i / 374, pos = i - q * 374;
                int h = pos / 11, w = pos - h * 11;
                dst[q * 443 + h * 13 + w] = src[i];
            }
        }
        __syncthreads();
        for (int khw = 0; khw < 108; ++khw) {
            const int off = (khw / 9) * 13 + (khw % 9);
            v8h a[5];
#pragma unroll
            for (int mt = 0; mt < 5; ++mt)
                a[mt] = *(const v8h*)(sA + (quad * 443 + pm[mt] + off) * 8);
            const unsigned short* bp = frag7
                + ((size_t)(khw * 2 + half) * 8) * 512 + lane * 8;
#pragma unroll
            for (int t = 0; t < 2; ++t) {
                const int nt = wave + t * 4;
                v8h b = *(const v8h*)(bp + nt * 512);
#pragma unroll
                for (int mt = 0; mt < 5; ++mt)
                    acc[t][mt] = __builtin_amdgcn_mfma_f32_16x16x32_f16(
                        a[mt], b, acc[t][mt], 0, 0, 0);
            }
        }
    }

    float s[2] = {0.f, 0.f};
#pragma unroll
    for (int t = 0; t < 2; ++t) {
        const float tb = tv[(wave + t * 4) * 16 + m];
#pragma unroll
        for (int mt = 0; mt < 5; ++mt) {
#pragma unroll
            for (int rr = 0; rr < 4; ++rr) {
                int p = mt * 16 + quad * 4 + rr;
                if (p < 69) s[t] += fmaxf(acc[t][mt][rr] + tb, 0.f);
            }
        }
    }
#pragma unroll
    for (int t = 0; t < 2; ++t) {
        s[t] += __shfl_xor(s[t], 16);
        s[t] += __shfl_xor(s[t], 32);
    }
    if (lane < 16) {
#pragma unroll
        for (int t = 0; t < 2; ++t)
            pooled[(size_t)n * 128 + (wave + t * 4) * 16 + lane] = s[t] * (1.f / 69.f);
    }
}

// ---------------------------------------------------------------------------
// logits = b8 + W8(25x128) . pooled
// ---------------------------------------------------------------------------
__global__ void logits_k(const float* __restrict__ pooled, const float* __restrict__ W8,
                         const float* __restrict__ b8, float* __restrict__ outg,
                         int total)
{
    int gid = blockIdx.x * 256 + threadIdx.x;
    if (gid >= total * 25) return;
    int nl = gid / 25, c = gid - nl * 25;
    const float* pp = pooled + (size_t)nl * 128;
    const float* wp = W8 + c * 128;
    float s = b8[c];
#pragma unroll
    for (int ci = 0; ci < 128; ci += 4) {
        float4 wv = *(const float4*)(wp + ci);
        float4 pv = *(const float4*)(pp + ci);
        s = fmaf(wv.x, pv.x, s);
        s = fmaf(wv.y, pv.y, s);
        s = fmaf(wv.z, pv.z, s);
        s = fmaf(wv.w, pv.w, s);
    }
    outg[(size_t)nl * 25 + c] = s;
}

// ---------------------------------------------------------------------------
extern "C" void kernel_launch(void* const* d_in, const int* in_sizes, int n_in,
                              void* d_out, int out_size, void* d_ws, size_t ws_size,
                              hipStream_t stream)
{
    const float* x = (const float*)d_in[0];
    const float* Wl[8]; const float* bl[8]; const float* gl[8];
    const float* bel[8]; const float* ml[8]; const float* vl[8];
    for (int i = 1; i <= 7; ++i) {
        int o = 2 + (i - 1) * 6;
        Wl[i]  = (const float*)d_in[o + 0];
        bl[i]  = (const float*)d_in[o + 1];
        gl[i]  = (const float*)d_in[o + 2];
        bel[i] = (const float*)d_in[o + 3];
        ml[i]  = (const float*)d_in[o + 4];
        vl[i]  = (const float*)d_in[o + 5];
    }
    const float* W8 = (const float*)d_in[44];
    const float* b8 = (const float*)d_in[45];
    float* ws = (float*)d_ws;

    // Workspace layout (float offsets); all 16B aligned.
    float* wr1 = ws + 0;        float* t1 = ws + 288;
    unsigned short* f2b = (unsigned short*)(ws + 320);
    float* t2 = ws + 4928;
    unsigned short* f3b = (unsigned short*)(ws + 4960);
    float* t3 = ws + 9568;
    unsigned short* f4b = (unsigned short*)(ws + 9600);
    float* t4 = ws + 14208;
    unsigned short* f5b = (unsigned short*)(ws + 14240);
    float* t5 = ws + 23456;
    unsigned short* f6b = (unsigned short*)(ws + 23520);
    float* t6 = ws + 41952;
    unsigned short* f7b = (unsigned short*)(ws + 42016);
    float* t7 = ws + 484384;
    const size_t WFL = 484512;

    // Persistent: c6 ([n][8cg][34r][11c][8] fp16) + pooled (fp32).
    unsigned short* c6buf = (unsigned short*)(ws + WFL);
    const size_t C6FL = (size_t)1728 * C6N / 2;
    float* pooled = ws + WFL + C6FL;
    const size_t FIXED = WFL + C6FL + (size_t)1728 * 128;

    size_t avail_fl = ws_size / 4;
    size_t buf_halves = (avail_fl > FIXED) ? (avail_fl - FIXED) * 2 : 0;
    int Cs = (int)(buf_halves / (size_t)SLOT);
    if (Cs < 1) Cs = 1;
    if (Cs > 1728) Cs = 1728;
    unsigned short* bufA = (unsigned short*)(ws + FIXED);   // region A (off 0)
    unsigned short* bufB = bufA + TA;                        // region B (off TA)

    auto g1 = [](int t) { return (t + 255) / 256; };

    // Weight repacks (once per call)
    repack_k<<<g1(288), 256, 0, stream>>>(Wl[1], bl[1], gl[1], bel[1], ml[1], vl[1], wr1, t1, 1, 9, 32);
    repack_mfma_k<<<g1(9216),  256, 0, stream>>>(Wl[2], bl[2], gl[2], bel[2], ml[2], vl[2], f2b, t2, 32, 2, 1);
    repack_mfma_k<<<g1(9216),  256, 0, stream>>>(Wl[3], bl[3], gl[3], bel[3], ml[3], vl[3], f3b, t3, 32, 2, 1);
    repack_mfma_k<<<g1(9216),  256, 0, stream>>>(Wl[4], bl[4], gl[4], bel[4], ml[4], vl[4], f4b, t4, 32, 2, 1);
    repack_mfma_k<<<g1(18432), 256, 0, stream>>>(Wl[5], bl[5], gl[5], bel[5], ml[5], vl[5], f5b, t5, 32, 4, 1);
    repack_mfma_k<<<g1(36864), 256, 0, stream>>>(Wl[6], bl[6], gl[6], bel[6], ml[6], vl[6], f6b, t6, 64, 4, 2);
    repack7_k<<<g1(884736), 256, 0, stream>>>(Wl[7], bl[7], gl[7], bel[7], ml[7], vl[7], f7b, t7);

    // Stage 1 (chunked, tight layouts):
    // fused conv1/2/3/4 x->B (9 bands), conv5 B->A, conv6 A->c6
    for (int c0 = 0; c0 < 1728; c0 += Cs) {
        int cn = (1728 - c0 < Cs) ? (1728 - c0) : Cs;
        conv1234f_k<<<dim3(9, cn), 256, 0, stream>>>(x, bufB, wr1, t1,
                                                     f2b, f3b, f4b, t2, t3, t4, c0);
        conv5m_k<<<dim3(8, cn), 256, 0, stream>>>(bufB, bufA, f5b, t5);
        conv6m_k<<<dim3(6, cn), 256, 0, stream>>>(bufA, c6buf + (size_t)c0 * C6N, f6b, t6);
    }

    // Stage 2: conv7 MFMA (+bias+relu+mean) over all samples, then logits.
    conv7mfma_k<<<1728, 256, 0, stream>>>(c6buf, pooled, f7b, t7);
    logits_k<<<g1(1728 * 25), 256, 0, stream>>>(pooled, W8, b8, (float*)d_out, 1728);
}

// Round 19
// 1133.482 us; speedup vs baseline: 1.1587x; 1.0924x over previous
//
#include <hip/hip_runtime.h>
#include <hip/hip_bf16.h>
#include <hip/hip_fp16.h>

// Tight stage-1 activations. Per-sample slot = region A + region B (halves).
// A: conv5 out [8cg][70][16][8]=71680. B: conv4-pool out [4cg][72][16][8]=36864.
// conv1/conv2/conv3 outs live in LDS only (fused band kernel).
#define TA 71680
#define SLOT 108544
// conv6 output halves per sample: [8 cg][34 rows][11 cols][8 ci], row stride 11
#define C6N 23936

typedef _Float16 v8h __attribute__((ext_vector_type(8)));
typedef float v4f __attribute__((ext_vector_type(4)));
typedef unsigned short u16x8 __attribute__((ext_vector_type(8)));

__device__ inline float h2f(unsigned short u) {
    union { unsigned short s; _Float16 h; } v; v.s = u; return (float)v.h;
}
__device__ inline unsigned short f2h(float f) {
    union { unsigned short s; _Float16 h; } v; v.h = (_Float16)f; return v.s;
}

// ---------------------------------------------------------------------------
// conv1 weight repack (fp32): [co][1][kh][kw] -> [k][co], BN folded; emits t.
// ---------------------------------------------------------------------------
__global__ void repack_k(const float* __restrict__ W, const float* __restrict__ bb,
                         const float* __restrict__ gg, const float* __restrict__ be,
                         const float* __restrict__ mm, const float* __restrict__ vv,
                         float* __restrict__ wOut, float* __restrict__ tOut,
                         int CIN, int KHW, int COUT)
{
    int gid = blockIdx.x * 256 + threadIdx.x;
    if (gid < COUT) {
        float s = gg[gid] * rsqrtf(vv[gid] + 1e-5f);
        tOut[gid] = (bb[gid] - mm[gid]) * s + be[gid];
    }
    int tot = CIN * KHW * COUT;
    if (gid >= tot) return;
    int co = gid % COUT;
    int rest = gid / COUT;
    int k = rest % KHW;
    int ci = rest / KHW;
    float s = gg[co] * rsqrtf(vv[co] + 1e-5f);
    wOut[gid] = W[(co * CIN + ci) * KHW + k] * s;
}

// ---------------------------------------------------------------------------
// MFMA B-fragment repack for 3x3 layers (conv2..conv6), fp16.
// ---------------------------------------------------------------------------
__global__ void repack_mfma_k(const float* __restrict__ W, const float* __restrict__ bb,
                              const float* __restrict__ gg, const float* __restrict__ be,
                              const float* __restrict__ mm, const float* __restrict__ vv,
                              unsigned short* __restrict__ frag, float* __restrict__ tOut,
                              int CIN, int NT, int HALVES)
{
    int gid = blockIdx.x * 256 + threadIdx.x;
    int COUT = NT * 16;
    if (gid < COUT) {
        float s = gg[gid] * rsqrtf(vv[gid] + 1e-5f);
        tOut[gid] = (bb[gid] - mm[gid]) * s + be[gid];
    }
    int tot = 9 * HALVES * NT * 512;
    if (gid >= tot) return;
    int j    = gid & 7;
    int lane = (gid >> 3) & 63;
    int nt   = (gid >> 9) % NT;
    int rest = (gid >> 9) / NT;
    int half = rest % HALVES;
    int khw  = rest / HALVES;
    int ci   = half * 32 + (lane >> 4) * 8 + j;
    int co   = nt * 16 + (lane & 15);
    int kh   = khw / 3, kw = khw % 3;
    float s = gg[co] * rsqrtf(vv[co] + 1e-5f);
    frag[gid] = f2h(W[((co * CIN + ci) * 3 + kh) * 3 + kw] * s);
}

// ---------------------------------------------------------------------------
// Conv7 weight repack into MFMA B-fragment order (12x9 kernel), fp16.
// ---------------------------------------------------------------------------
__global__ void repack7_k(const float* __restrict__ W, const float* __restrict__ bb,
                          const float* __restrict__ gg, const float* __restrict__ be,
                          const float* __restrict__ mm, const float* __restrict__ vv,
                          unsigned short* __restrict__ frag, float* __restrict__ tOut)
{
    int gid = blockIdx.x * 256 + threadIdx.x;
    if (gid < 128) {
        float s = gg[gid] * rsqrtf(vv[gid] + 1e-5f);
        tOut[gid] = (bb[gid] - mm[gid]) * s + be[gid];
    }
    if (gid >= 884736) return;           // 108*2*8*64*8
    int j    = gid & 7;
    int lane = (gid >> 3) & 63;
    int nt   = (gid >> 9) & 7;
    int half = (gid >> 12) & 1;
    int khw  = gid >> 13;
    int co   = nt * 16 + (lane & 15);
    int ci   = half * 32 + (lane >> 4) * 8 + j;
    int kh   = khw / 9, kw = khw - kh * 9;
    float s = gg[co] * rsqrtf(vv[co] + 1e-5f);
    frag[gid] = f2h(W[((co * 64 + ci) * 12 + kh) * 9 + kw] * s);
}

// ---------------------------------------------------------------------------
// FUSED conv1+conv2+conv3+conv4(+pool) per (band, sample).
// Phase 0: stage 17x24 fp32 x-slab to LDS (zero-filled for T-pad / row OOB)
//          + zero s2 halo cols.
// Phase 1: conv1 in-register (374 slab pos x 32ch) -> s1 slab. Explicit
//          window-col mask (conv SAME pad at cols -1/15 is ALWAYS zero; the
//          T-pad is a separate mask baked into the x-slab zero-fill).
// Phases 2-4: conv2 -> s2 (LDS), conv3 -> s3 (aliases s1), conv4+pool -> B.
// LDS (16B units): s1 = 4q x 375 (22r x 17c), s2 @1500 = 4 x 341 (20r x 17c),
// s3 aliases s1 = 4 x 307 (18r x 17c); sx (fp32 x-slab) after s2: 1632 B.
// R14-measured-best geometry (1129.9us total); R15-R18 variants (conv1-MFMA,
// 12 bands, balanced conv1 split) all regressed -- this is the local optimum.
// ---------------------------------------------------------------------------
__global__ __launch_bounds__(256) void conv1234f_k(
    const float* __restrict__ x, unsigned short* __restrict__ out,
    const float* __restrict__ wr1, const float* __restrict__ t1v,
    const unsigned short* __restrict__ f2, const unsigned short* __restrict__ f3,
    const unsigned short* __restrict__ f4, const float* __restrict__ t2,
    const float* __restrict__ t3, const float* __restrict__ t4, int c0)
{
    __shared__ __align__(16) unsigned short sm[23728];   // 45824B slabs + sx
    float* sx = (float*)(sm + 22912);                    // 17 x 24 fp32
    const int band = blockIdx.x;
    const int nl = blockIdx.y;
    const int n = c0 + nl;
    const int tid = threadIdx.x;
    const int wave = tid >> 6, lane = tid & 63;
    const int m = lane & 15, quad = lane >> 4;
    const int b = n / 108, t = n - b * 108;

    // Phase 0: x-slab staging + s2 halo zero.
    {
        float4* dst = (float4*)sm;
        for (int i = tid; i < 568; i += 256) {
            if (i < 408) {
                int tp = i / 24, fp = i - tp * 24;
                int tt = t - 8 + tp;
                int ff = band * 16 - 4 + fp;
                float v = 0.f;
                if (tt >= 0 && tt < 108 && ff >= 0 && ff < 144)
                    v = x[(b * 108 + tt) * 144 + ff];
                sx[tp * 24 + fp] = v;
            } else {
                int j = i - 408;                 // 4q x 20r x 2cols = 160
                int q = j / 40, jj = j - q * 40;
                int rr = jj >> 1, c2 = (jj & 1) * 16;
                dst[1500 + q * 341 + rr * 17 + c2] = (float4){0.f,0.f,0.f,0.f};
            }
        }
    }
    __syncthreads();

    // Phase 1: conv1 -> s1 slab [4q][22r][17c][8].
    for (int e = tid; e < 374; e += 256) {
        int r = e / 17, cp = e - r * 17;
        int gr = band * 16 - 3 + r;
        int gc = cp - 1;
        float acc1[32];
#pragma unroll
        for (int i = 0; i < 32; ++i) acc1[i] = 0.f;
        bool valid = (gr >= 0 && gr < 144 && gc >= 0 && gc < 15);
        if (valid) {
#pragma unroll
            for (int kh = 0; kh < 3; ++kh) {
                int fp = r + kh;
#pragma unroll
                for (int kw = 0; kw < 3; ++kw) {
                    int c = gc + kw - 1;
                    if (c < 0 || c >= 15) continue;   // conv SAME pad
                    float xv = sx[(c + 1) * 24 + fp]; // T-pad zero-filled
                    const float* wp = wr1 + (kh * 3 + kw) * 32;
#pragma unroll
                    for (int q8 = 0; q8 < 8; ++q8) {
                        float4 wv = *(const float4*)(wp + q8 * 4);
                        acc1[q8 * 4 + 0] = fmaf(xv, wv.x, acc1[q8 * 4 + 0]);
                        acc1[q8 * 4 + 1] = fmaf(xv, wv.y, acc1[q8 * 4 + 1]);
                        acc1[q8 * 4 + 2] = fmaf(xv, wv.z, acc1[q8 * 4 + 2]);
                        acc1[q8 * 4 + 3] = fmaf(xv, wv.w, acc1[q8 * 4 + 3]);
                    }
                }
            }
        }
#pragma unroll
        for (int q2 = 0; q2 < 4; ++q2) {
            u16x8 pk;
#pragma unroll
            for (int c8 = 0; c8 < 8; ++c8)
                pk[c8] = valid ? f2h(fmaxf(acc1[q2 * 8 + c8] + t1v[q2 * 8 + c8], 0.f))
                               : (unsigned short)0;
            *(u16x8*)(sm + q2 * 3000 + (r * 17 + cp) * 8) = pk;
        }
    }
    __syncthreads();

    v4f acc[2][5];
    int mt[5], la[5];

    // ---------------- conv2: 20 rows x 15 cols = 300 pos, 19 tiles ----------
#pragma unroll
    for (int wt = 0; wt < 5; ++wt) {
        int tt = wave * 5 + wt; if (tt > 18) tt = 18;
        mt[wt] = tt;
        int p = tt * 16 + m; if (p >= 300) p = 299;
        int r = p / 15, c = p - r * 15;
        la[wt] = r * 17 + c;
    }
#pragma unroll
    for (int nt = 0; nt < 2; ++nt)
#pragma unroll
        for (int wt = 0; wt < 5; ++wt) acc[nt][wt] = (v4f){0.f,0.f,0.f,0.f};
#pragma unroll
    for (int khw = 0; khw < 9; ++khw) {
        const int sh = (khw / 3) * 17 + (khw % 3);
        v8h a[5];
#pragma unroll
        for (int wt = 0; wt < 5; ++wt)
            a[wt] = *(const v8h*)(sm + quad * 3000 + (la[wt] + sh) * 8);
#pragma unroll
        for (int nt = 0; nt < 2; ++nt) {
            v8h bb = *(const v8h*)(f2 + (khw * 2 + nt) * 512 + lane * 8);
#pragma unroll
            for (int wt = 0; wt < 5; ++wt)
                acc[nt][wt] = __builtin_amdgcn_mfma_f32_16x16x32_f16(a[wt], bb, acc[nt][wt], 0, 0, 0);
        }
    }
#pragma unroll
    for (int wt = 0; wt < 5; ++wt) {
        const int pb = mt[wt] * 16 + quad * 4;
#pragma unroll
        for (int nt = 0; nt < 2; ++nt) {
            const int co = nt * 16 + m;
            const float tb = t2[co];
            unsigned short* ob = sm + 12000 + (co >> 3) * 2728 + (co & 7);
#pragma unroll
            for (int reg = 0; reg < 4; ++reg) {
                int p = pb + reg;
                if (p < 300) {
                    int r = p / 15, c = p - r * 15;
                    ob[(r * 17 + c + 1) * 8] = f2h(fmaxf(acc[nt][wt][reg] + tb, 0.f));
                }
            }
        }
    }
    __syncthreads();

    // zero s3 halo cols (s3 aliases dead conv1 slab)
    if (tid < 144) {
        int q = tid / 36, jj = tid - q * 36;
        int rr = jj >> 1, c2 = (jj & 1) * 16;
        *((float4*)sm + q * 307 + rr * 17 + c2) = (float4){0.f,0.f,0.f,0.f};
    }

    // ---------------- conv3: 18 rows x 15 cols = 270 pos, 17 tiles ----------
#pragma unroll
    for (int wt = 0; wt < 5; ++wt) {
        int tt = wave * 5 + wt; if (tt > 16) tt = 16;
        mt[wt] = tt;
        int p = tt * 16 + m; if (p >= 270) p = 269;
        int r = p / 15, c = p - r * 15;
        la[wt] = r * 17 + c;
    }
#pragma unroll
    for (int nt = 0; nt < 2; ++nt)
#pragma unroll
        for (int wt = 0; wt < 5; ++wt) acc[nt][wt] = (v4f){0.f,0.f,0.f,0.f};
#pragma unroll
    for (int khw = 0; khw < 9; ++khw) {
        const int sh = (khw / 3) * 17 + (khw % 3);
        v8h a[5];
#pragma unroll
        for (int wt = 0; wt < 5; ++wt)
            a[wt] = *(const v8h*)(sm + 12000 + quad * 2728 + (la[wt] + sh) * 8);
#pragma unroll
        for (int nt = 0; nt < 2; ++nt) {
            v8h bb = *(const v8h*)(f3 + (khw * 2 + nt) * 512 + lane * 8);
#pragma unroll
            for (int wt = 0; wt < 5; ++wt)
                acc[nt][wt] = __builtin_amdgcn_mfma_f32_16x16x32_f16(a[wt], bb, acc[nt][wt], 0, 0, 0);
        }
    }
#pragma unroll
    for (int wt = 0; wt < 5; ++wt) {
        const int pb = mt[wt] * 16 + quad * 4;
#pragma unroll
        for (int nt = 0; nt < 2; ++nt) {
            const int co = nt * 16 + m;
            const float tb = t3[co];
            unsigned short* ob = sm + (co >> 3) * 2456 + (co & 7);
#pragma unroll
            for (int reg = 0; reg < 4; ++reg) {
                int p = pb + reg;
                if (p < 270) {
                    int r = p / 15, c = p - r * 15;
                    ob[(r * 17 + c + 1) * 8] = f2h(fmaxf(acc[nt][wt][reg] + tb, 0.f));
                }
            }
        }
    }
    __syncthreads();

    // ---------------- conv4 + pool: 240 pos (pr,w,s ordered), 15 tiles ------
    int mt4[4], la4[4];
#pragma unroll
    for (int wt = 0; wt < 4; ++wt) {
        int tt = wave * 4 + wt; if (tt > 14) tt = 14;
        mt4[wt] = tt;
        int p = tt * 16 + m;
        int pr = p / 30, rem = p - pr * 30;
        int w = rem >> 1, r4 = pr * 2 + (rem & 1);
        la4[wt] = r4 * 17 + w;
    }
    v4f acc4[2][4];
#pragma unroll
    for (int nt = 0; nt < 2; ++nt)
#pragma unroll
        for (int wt = 0; wt < 4; ++wt) acc4[nt][wt] = (v4f){0.f,0.f,0.f,0.f};
#pragma unroll
    for (int khw = 0; khw < 9; ++khw) {
        const int sh = (khw / 3) * 17 + (khw % 3);
        v8h a[4];
#pragma unroll
        for (int wt = 0; wt < 4; ++wt)
            a[wt] = *(const v8h*)(sm + quad * 2456 + (la4[wt] + sh) * 8);
#pragma unroll
        for (int nt = 0; nt < 2; ++nt) {
            v8h bb = *(const v8h*)(f4 + (khw * 2 + nt) * 512 + lane * 8);
#pragma unroll
            for (int wt = 0; wt < 4; ++wt)
                acc4[nt][wt] = __builtin_amdgcn_mfma_f32_16x16x32_f16(a[wt], bb, acc4[nt][wt], 0, 0, 0);
        }
    }
    unsigned short* outN = out + (size_t)nl * SLOT;
#pragma unroll
    for (int wt = 0; wt < 4; ++wt) {
        const int pb = band * 240 + mt4[wt] * 16 + quad * 4;
#pragma unroll
        for (int nt = 0; nt < 2; ++nt) {
            const int co = nt * 16 + m;
            const float tb = t4[co];
            unsigned short* ob = outN + (co >> 3) * 9216 + (co & 7);
#pragma unroll
            for (int pi = 0; pi < 2; ++pi) {
                int pe = pb + pi * 2;
                int pr = pe / 30, rem = pe - pr * 30, w = rem >> 1;
                float v0 = fmaxf(acc4[nt][wt][pi * 2] + tb, 0.f);
                float v1 = fmaxf(acc4[nt][wt][pi * 2 + 1] + tb, 0.f);
                ob[(pr * 16 + w) * 8] = f2h(fmaxf(v0, v1));
            }
        }
    }
}

// ---------------------------------------------------------------------------
// conv5 MFMA: 32->64ch 3x3 VALID, in [4cg][72][16][8] -> out [8cg][70][16][8].
// ---------------------------------------------------------------------------
__global__ __launch_bounds__(256) void conv5m_k(
    const unsigned short* __restrict__ in, unsigned short* __restrict__ out,
    const unsigned short* __restrict__ frag, const float* __restrict__ tv)
{
    const int n = blockIdx.y;
    const int tid = threadIdx.x;
    const int wave = tid >> 6, lane = tid & 63;
    const int m = lane & 15, quad = lane >> 4;
    const unsigned short* inN = in + (size_t)n * SLOT + quad * 9216;

    int mt[2], a0[2];
#pragma unroll
    for (int wt = 0; wt < 2; ++wt) {
        int t = blockIdx.x * 8 + wave * 2 + wt; if (t > 56) t = 56;
        mt[wt] = t;
        int p = t * 16 + m; if (p > 909) p = 909;
        int r = p / 13, w = p - r * 13;
        a0[wt] = (r * 16 + w) * 8;
    }

    v4f acc[4][2];
#pragma unroll
    for (int nt = 0; nt < 4; ++nt)
#pragma unroll
        for (int wt = 0; wt < 2; ++wt) acc[nt][wt] = (v4f){0.f,0.f,0.f,0.f};

#pragma unroll
    for (int khw = 0; khw < 9; ++khw) {
        const int shift = ((khw / 3) * 16 + (khw % 3)) * 8;
        v8h a[2];
#pragma unroll
        for (int wt = 0; wt < 2; ++wt)
            a[wt] = *(const v8h*)(inN + a0[wt] + shift);
#pragma unroll
        for (int nt = 0; nt < 4; ++nt) {
            v8h b = *(const v8h*)(frag + (khw * 4 + nt) * 512 + lane * 8);
#pragma unroll
            for (int wt = 0; wt < 2; ++wt)
                acc[nt][wt] = __builtin_amdgcn_mfma_f32_16x16x32_f16(a[wt], b, acc[nt][wt], 0, 0, 0);
        }
    }

    unsigned short* outN = out + (size_t)n * SLOT;
#pragma unroll
    for (int wt = 0; wt < 2; ++wt) {
        const int pb = mt[wt] * 16 + quad * 4;
#pragma unroll
        for (int nt = 0; nt < 4; ++nt) {
            const int co = nt * 16 + m;
            const float tb = tv[co];
            unsigned short* ob = outN + (co >> 3) * 8960 + (co & 7);
#pragma unroll
            for (int reg = 0; reg < 4; ++reg) {
                int p = pb + reg;
                if (p < 910) {
                    int r = p / 13, w = p - r * 13;
                    ob[(r * 16 + w) * 8] = f2h(fmaxf(acc[nt][wt][reg] + tb, 0.f));
                }
            }
        }
    }
}

// ---------------------------------------------------------------------------
// conv6 MFMA (+fused pool) -> c6 [8cg][34r][11c][8], row stride 11.
// ---------------------------------------------------------------------------
__global__ __launch_bounds__(256) void conv6m_k(
    const unsigned short* __restrict__ in, unsigned short* __restrict__ c6,
    const unsigned short* __restrict__ frag, const float* __restrict__ tv)
{
    const int n = blockIdx.y;
    const int tid = threadIdx.x;
    const int wave = tid >> 6, lane = tid & 63;
    const int m = lane & 15, quad = lane >> 4;
    const unsigned short* inN = in + (size_t)n * SLOT;

    int mt[2], a0[2];
#pragma unroll
    for (int wt = 0; wt < 2; ++wt) {
        int t = blockIdx.x * 8 + wave * 2 + wt; if (t > 46) t = 46;
        mt[wt] = t;
        int p = t * 16 + m; if (p > 747) p = 747;
        int pr = p / 22, rem = p - pr * 22;
        int w = rem >> 1, r = pr * 2 + (rem & 1);
        a0[wt] = (r * 16 + w) * 8;
    }

    v4f acc[4][2];
#pragma unroll
    for (int nt = 0; nt < 4; ++nt)
#pragma unroll
        for (int wt = 0; wt < 2; ++wt) acc[nt][wt] = (v4f){0.f,0.f,0.f,0.f};

#pragma unroll
    for (int khw = 0; khw < 9; ++khw) {
        const int shift = ((khw / 3) * 16 + (khw % 3)) * 8;
#pragma unroll
        for (int half = 0; half < 2; ++half) {
            const unsigned short* ip = inN + (half * 4 + quad) * 8960 + shift;
            v8h a[2];
#pragma unroll
            for (int wt = 0; wt < 2; ++wt)
                a[wt] = *(const v8h*)(ip + a0[wt]);
#pragma unroll
            for (int nt = 0; nt < 4; ++nt) {
                v8h b = *(const v8h*)(frag + ((khw * 2 + half) * 4 + nt) * 512 + lane * 8);
#pragma unroll
                for (int wt = 0; wt < 2; ++wt)
                    acc[nt][wt] = __builtin_amdgcn_mfma_f32_16x16x32_f16(a[wt], b, acc[nt][wt], 0, 0, 0);
            }
        }
    }

    unsigned short* outN = c6 + (size_t)n * C6N;
#pragma unroll
    for (int wt = 0; wt < 2; ++wt) {
        const int pb = mt[wt] * 16 + quad * 4;
#pragma unroll
        for (int nt = 0; nt < 4; ++nt) {
            const int co = nt * 16 + m;
            const float tb = tv[co];
            unsigned short* ob = outN + (co >> 3) * 2992 + (co & 7);
#pragma unroll
            for (int pi = 0; pi < 2; ++pi) {
                int pe = pb + pi * 2;
                if (pe < 748) {
                    int pr = pe / 22, rem = pe - pr * 22, w = rem >> 1;
                    float v0 = fmaxf(acc[nt][wt][pi * 2] + tb, 0.f);
                    float v1 = fmaxf(acc[nt][wt][pi * 2 + 1] + tb, 0.f);
                    ob[(pr * 11 + w) * 8] = f2h(fmaxf(v0, v1));
                }
            }
        }
    }
}

// ---------------------------------------------------------------------------
// Conv7 MFMA GEMM — R12-measured-best config (48 VGPR, 42% occ, 196us):
// LDS 443 quad stride / 13 row stride; staging remaps from stride-11 c6.
// ---------------------------------------------------------------------------
__global__ __launch_bounds__(256) void conv7mfma_k(
    const unsigned short* __restrict__ c6, float* __restrict__ pooled,
    const unsigned short* __restrict__ frag7, const float* __restrict__ tv)
{
    __shared__ __align__(16) unsigned short sA[14176];  // 4 x 443 x 8
    const int n = blockIdx.x;
    const int tid = threadIdx.x;
    const int wave = tid >> 6;
    const int lane = tid & 63;
    const int m = lane & 15;
    const int quad = lane >> 4;

    int pm[5];
#pragma unroll
    for (int mt = 0; mt < 5; ++mt) {
        int p = mt * 16 + m;
        if (p >= 69) p = 0;
        pm[mt] = (p / 3) * 13 + (p % 3);
    }

    v4f acc[2][5];
#pragma unroll
    for (int t = 0; t < 2; ++t)
#pragma unroll
        for (int mt = 0; mt < 5; ++mt)
            acc[t][mt] = (v4f){0.f, 0.f, 0.f, 0.f};

    for (int half = 0; half < 2; ++half) {
        __syncthreads();
        {
            const float4* src = (const float4*)(c6 + (size_t)n * C6N + half * 11968);
            float4* dst = (float4*)sA;
            for (int i = tid; i < 1496; i += 256) {
                int q = i / 374, pos = i - q * 374;
                int h = pos / 11, w = pos - h * 11;
                dst[q * 443 + h * 13 + w] = src[i];
            }
        }
        __syncthreads();
        for (int khw = 0; khw < 108; ++khw) {
            const int off = (khw / 9) * 13 + (khw % 9);
            v8h a[5];
#pragma unroll
            for (int mt = 0; mt < 5; ++mt)
                a[mt] = *(const v8h*)(sA + (quad * 443 + pm[mt] + off) * 8);
            const unsigned short* bp = frag7
                + ((size_t)(khw * 2 + half) * 8) * 512 + lane * 8;
#pragma unroll
            for (int t = 0; t < 2; ++t) {
                const int nt = wave + t * 4;
                v8h b = *(const v8h*)(bp + nt * 512);
#pragma unroll
                for (int mt = 0; mt < 5; ++mt)
                    acc[t][mt] = __builtin_amdgcn_mfma_f32_16x16x32_f16(
                        a[mt], b, acc[t][mt], 0, 0, 0);
            }
        }
    }

    float s[2] = {0.f, 0.f};
#pragma unroll
    for (int t = 0; t < 2; ++t) {
        const float tb = tv[(wave + t * 4) * 16 + m];
#pragma unroll
        for (int mt = 0; mt < 5; ++mt) {
#pragma unroll
            for (int rr = 0; rr < 4; ++rr) {
                int p = mt * 16 + quad * 4 + rr;
                if (p < 69) s[t] += fmaxf(acc[t][mt][rr] + tb, 0.f);
            }
        }
    }
#pragma unroll
    for (int t = 0; t < 2; ++t) {
        s[t] += __shfl_xor(s[t], 16);
        s[t] += __shfl_xor(s[t], 32);
    }
    if (lane < 16) {
#pragma unroll
        for (int t = 0; t < 2; ++t)
            pooled[(size_t)n * 128 + (wave + t * 4) * 16 + lane] = s[t] * (1.f / 69.f);
    }
}

// ---------------------------------------------------------------------------
// logits = b8 + W8(25x128) . pooled
// ---------------------------------------------------------------------------
__global__ void logits_k(const float* __restrict__ pooled, const float* __restrict__ W8,
                         const float* __restrict__ b8, float* __restrict__ outg,
                         int total)
{
    int gid = blockIdx.x * 256 + threadIdx.x;
    if (gid >= total * 25) return;
    int nl = gid / 25, c = gid - nl * 25;
    const float* pp = pooled + (size_t)nl * 128;
    const float* wp = W8 + c * 128;
    float s = b8[c];
#pragma unroll
    for (int ci = 0; ci < 128; ci += 4) {
        float4 wv = *(const float4*)(wp + ci);
        float4 pv = *(const float4*)(pp + ci);
        s = fmaf(wv.x, pv.x, s);
        s = fmaf(wv.y, pv.y, s);
        s = fmaf(wv.z, pv.z, s);
        s = fmaf(wv.w, pv.w, s);
    }
    outg[(size_t)nl * 25 + c] = s;
}

// ---------------------------------------------------------------------------
extern "C" void kernel_launch(void* const* d_in, const int* in_sizes, int n_in,
                              void* d_out, int out_size, void* d_ws, size_t ws_size,
                              hipStream_t stream)
{
    const float* x = (const float*)d_in[0];
    const float* Wl[8]; const float* bl[8]; const float* gl[8];
    const float* bel[8]; const float* ml[8]; const float* vl[8];
    for (int i = 1; i <= 7; ++i) {
        int o = 2 + (i - 1) * 6;
        Wl[i]  = (const float*)d_in[o + 0];
        bl[i]  = (const float*)d_in[o + 1];
        gl[i]  = (const float*)d_in[o + 2];
        bel[i] = (const float*)d_in[o + 3];
        ml[i]  = (const float*)d_in[o + 4];
        vl[i]  = (const float*)d_in[o + 5];
    }
    const float* W8 = (const float*)d_in[44];
    const float* b8 = (const float*)d_in[45];
    float* ws = (float*)d_ws;

    // Workspace layout (float offsets); all 16B aligned.
    float* wr1 = ws + 0;        float* t1 = ws + 288;
    unsigned short* f2b = (unsigned short*)(ws + 320);
    float* t2 = ws + 4928;
    unsigned short* f3b = (unsigned short*)(ws + 4960);
    float* t3 = ws + 9568;
    unsigned short* f4b = (unsigned short*)(ws + 9600);
    float* t4 = ws + 14208;
    unsigned short* f5b = (unsigned short*)(ws + 14240);
    float* t5 = ws + 23456;
    unsigned short* f6b = (unsigned short*)(ws + 23520);
    float* t6 = ws + 41952;
    unsigned short* f7b = (unsigned short*)(ws + 42016);
    float* t7 = ws + 484384;
    const size_t WFL = 484512;

    // Persistent: c6 ([n][8cg][34r][11c][8] fp16) + pooled (fp32).
    unsigned short* c6buf = (unsigned short*)(ws + WFL);
    const size_t C6FL = (size_t)1728 * C6N / 2;
    float* pooled = ws + WFL + C6FL;
    const size_t FIXED = WFL + C6FL + (size_t)1728 * 128;

    size_t avail_fl = ws_size / 4;
    size_t buf_halves = (avail_fl > FIXED) ? (avail_fl - FIXED) * 2 : 0;
    int Cs = (int)(buf_halves / (size_t)SLOT);
    if (Cs < 1) Cs = 1;
    if (Cs > 1728) Cs = 1728;
    unsigned short* bufA = (unsigned short*)(ws + FIXED);   // region A (off 0)
    unsigned short* bufB = bufA + TA;                        // region B (off TA)

    auto g1 = [](int t) { return (t + 255) / 256; };

    // Weight repacks (once per call)
    repack_k<<<g1(288), 256, 0, stream>>>(Wl[1], bl[1], gl[1], bel[1], ml[1], vl[1], wr1, t1, 1, 9, 32);
    repack_mfma_k<<<g1(9216),  256, 0, stream>>>(Wl[2], bl[2], gl[2], bel[2], ml[2], vl[2], f2b, t2, 32, 2, 1);
    repack_mfma_k<<<g1(9216),  256, 0, stream>>>(Wl[3], bl[3], gl[3], bel[3], ml[3], vl[3], f3b, t3, 32, 2, 1);
    repack_mfma_k<<<g1(9216),  256, 0, stream>>>(Wl[4], bl[4], gl[4], bel[4], ml[4], vl[4], f4b, t4, 32, 2, 1);
    repack_mfma_k<<<g1(18432), 256, 0, stream>>>(Wl[5], bl[5], gl[5], bel[5], ml[5], vl[5], f5b, t5, 32, 4, 1);
    repack_mfma_k<<<g1(36864), 256, 0, stream>>>(Wl[6], bl[6], gl[6], bel[6], ml[6], vl[6], f6b, t6, 64, 4, 2);
    repack7_k<<<g1(884736), 256, 0, stream>>>(Wl[7], bl[7], gl[7], bel[7], ml[7], vl[7], f7b, t7);

    // Stage 1 (chunked, tight layouts):
    // fused conv1/2/3/4 x->B (9 bands), conv5 B->A, conv6 A->c6
    for (int c0 = 0; c0 < 1728; c0 += Cs) {
        int cn = (1728 - c0 < Cs) ? (1728 - c0) : Cs;
        conv1234f_k<<<dim3(9, cn), 256, 0, stream>>>(x, bufB, wr1, t1,
                                                     f2b, f3b, f4b, t2, t3, t4, c0);
        conv5m_k<<<dim3(8, cn), 256, 0, stream>>>(bufB, bufA, f5b, t5);
        conv6m_k<<<dim3(6, cn), 256, 0, stream>>>(bufA, c6buf + (size_t)c0 * C6N, f6b, t6);
    }

    // Stage 2: conv7 MFMA (+bias+relu+mean) over all samples, then logits.
    conv7mfma_k<<<1728, 256, 0, stream>>>(c6buf, pooled, f7b, t7);
    logits_k<<<g1(1728 * 25), 256, 0, stream>>>(pooled, W8, b8, (float*)d_out, 1728);
}